// Round 4
// baseline (2099.016 us; speedup 1.0000x reference)
//
#include <hip/hip_runtime.h>
#include <hip/hip_cooperative_groups.h>
#include <math.h>

namespace cg = cooperative_groups;

#define NEGV -10000000.0f

constexpr int B_ = 8, T_ = 16;
constexpr int QALL = 256, QRES = 128, QARG = 192;
constexpr int STATE = 256, VOCAB = 10000;
constexpr int WT = 128;
constexpr int NWT = (VOCAB + WT - 1) / WT;   // 79
constexpr int NTERM = B_ * T_;               // 128 word positions
constexpr int GRID_COOP = 240;

// ---- workspace layout (units of 4 bytes) ----
constexpr size_t OFF_CHART = 0;                                    // chart[lev][s][b][a]
constexpr size_t CHART_SZ  = (size_t)T_ * T_ * B_ * QALL;          // 524288
constexpr size_t OFF_EGR   = OFF_CHART + CHART_SZ;                 // exp(G_rarg) [j][r]
constexpr size_t OFF_EGL   = OFF_EGR + (size_t)QARG * QRES;
constexpr size_t OFF_LF    = OFF_EGL + (size_t)QARG * QRES;        // lfunc T [j][r] (int)
constexpr size_t OFF_RF    = OFF_LF + (size_t)QARG * QRES;
constexpr size_t OFF_S0    = OFF_RF + (size_t)QARG * QRES;         // split0 (256)
constexpr size_t OFF_S1    = OFF_S0 + QALL;                        // split1 (256)
constexpr size_t OFF_PM    = OFF_S1 + QALL;                        // emit partial max [a][80]
constexpr size_t OFF_PS    = OFF_PM + (size_t)QALL * 80;           // emit partial sum [a][80]
constexpr size_t OFF_TERM  = OFF_PS + (size_t)QALL * 80;           // raw term logits [item][a]
constexpr size_t OFF_RMAX  = OFF_TERM + (size_t)NTERM * QALL;      // rowmax[lev][s][b]
constexpr size_t OFF_ACC   = OFF_RMAX + (size_t)T_ * T_ * B_;      // exp-sum acc [slot][r]
constexpr size_t ACC_SZ    = 960 * 128;
constexpr size_t OFF_CNT   = OFF_ACC + ACC_SZ;                     // arrival counters (960 ints)

__device__ __forceinline__ size_t chIdx(int lev, int s, int b) {
    return OFF_CHART + ((size_t)((lev * 16 + s) * 8 + b)) * 256;
}

__device__ __forceinline__ float waveMax(float v) {
    #pragma unroll
    for (int m = 32; m >= 1; m >>= 1) v = fmaxf(v, __shfl_xor(v, m, 64));
    return v;
}
__device__ __forceinline__ float waveSum(float v) {
    #pragma unroll
    for (int m = 32; m >= 1; m >>= 1) v += __shfl_xor(v, m, 64);
    return v;
}
__device__ __forceinline__ float blockMax(float v, float* scr, int nw) {
    int lane = threadIdx.x & 63, w = threadIdx.x >> 6;
    v = waveMax(v);
    if (lane == 0) scr[w] = v;
    __syncthreads();
    float r = scr[0];
    for (int i = 1; i < nw; i++) r = fmaxf(r, scr[i]);
    __syncthreads();
    return r;
}
__device__ __forceinline__ float blockSum(float v, float* scr, int nw) {
    int lane = threadIdx.x & 63, w = threadIdx.x >> 6;
    v = waveSum(v);
    if (lane == 0) scr[w] = v;
    __syncthreads();
    float r = 0.f;
    for (int i = 0; i < nw; i++) r += scr[i];
    __syncthreads();
    return r;
}

// ================= front kernel: emit GEMM (+ raw term epilogue) + prep_g =================
__global__ __launch_bounds__(256) void front_kernel(
        const int* __restrict__ words, const float* __restrict__ nt_emb,
        const float* __restrict__ W_emit, const float* __restrict__ b_emit,
        const float* __restrict__ rule_W, const float* __restrict__ rule_b,
        const float* __restrict__ assoc,
        const float* __restrict__ larg_mask, const float* __restrict__ rarg_mask,
        const int* __restrict__ lfunc, const int* __restrict__ rfunc,
        float* __restrict__ ws) {
    __shared__ float As[16][64];
    __shared__ float Bs[16][128];
    __shared__ float redM[64][16], redS[64][16];
    __shared__ int wordsS[128];
    __shared__ float scr[4];
    int bid = blockIdx.x, t = threadIdx.x;

    if (bid < 316) {
        // ---- emit role ----
        int wt = bid % 79, at = bid / 79;
        int tx = t & 15, ty = t >> 4;
        if (t < 128) wordsS[t] = words[t];
        float acc[4][8];
        #pragma unroll
        for (int i = 0; i < 4; i++)
            #pragma unroll
            for (int j = 0; j < 8; j++) acc[i][j] = 0.f;
        int wbase = wt * WT, abase = at * 64;
        for (int k0 = 0; k0 < STATE; k0 += 16) {
            {
                int idx = t * 4;
                int kk = idx & 15, aa = idx >> 4;
                float4 v = *(const float4*)&nt_emb[(abase + aa) * STATE + k0 + kk];
                As[kk + 0][aa] = v.x; As[kk + 1][aa] = v.y; As[kk + 2][aa] = v.z; As[kk + 3][aa] = v.w;
            }
            {
                int idx = t * 8;
                int kk = idx >> 7, ww = idx & 127;
                int w = wbase + ww;
                const float* src = &W_emit[(size_t)(k0 + kk) * VOCAB + w];
                float4 v0, v1;
                if (w + 7 < VOCAB) {
                    v0 = *(const float4*)src;
                    v1 = *(const float4*)(src + 4);
                } else {
                    float tv[8];
                    #pragma unroll
                    for (int q = 0; q < 8; q++) tv[q] = (w + q < VOCAB) ? src[q] : 0.f;
                    v0 = make_float4(tv[0], tv[1], tv[2], tv[3]);
                    v1 = make_float4(tv[4], tv[5], tv[6], tv[7]);
                }
                float* dst = &Bs[kk][ww];
                ((float4*)dst)[0] = v0;
                ((float4*)dst)[1] = v1;
            }
            __syncthreads();
            #pragma unroll
            for (int kk = 0; kk < 16; kk++) {
                float a4[4], b8[8];
                #pragma unroll
                for (int i = 0; i < 4; i++) a4[i] = As[kk][ty * 4 + i];
                #pragma unroll
                for (int j = 0; j < 8; j++) b8[j] = Bs[kk][tx * 8 + j];
                #pragma unroll
                for (int i = 0; i < 4; i++)
                    #pragma unroll
                    for (int j = 0; j < 8; j++) acc[i][j] += a4[i] * b8[j];
            }
            __syncthreads();
        }
        float be[8];
        #pragma unroll
        for (int j = 0; j < 8; j++) {
            int w = wbase + tx * 8 + j;
            be[j] = (w < VOCAB) ? b_emit[w] : 0.f;
        }
        #pragma unroll
        for (int i = 0; i < 4; i++) {
            float mloc = -3.0e38f;
            #pragma unroll
            for (int j = 0; j < 8; j++) {
                int w = wbase + tx * 8 + j;
                if (w < VOCAB) {
                    float v = acc[i][j] + be[j];
                    acc[i][j] = v;
                    mloc = fmaxf(mloc, v);
                }
            }
            float sloc = 0.f;
            #pragma unroll
            for (int j = 0; j < 8; j++) {
                int w = wbase + tx * 8 + j;
                if (w < VOCAB) sloc += expf(acc[i][j] - mloc);
            }
            redM[ty * 4 + i][tx] = mloc;
            redS[ty * 4 + i][tx] = sloc;
        }
        // raw term logits for word positions in this w-tile
        for (int it = 0; it < 128; it++) {
            int w = wordsS[it];
            int d = w - wbase;
            if (d >= 0 && d < 128 && (d >> 3) == tx) {
                int j = d & 7;
                #pragma unroll
                for (int i = 0; i < 4; i++)
                    ws[OFF_TERM + (size_t)it * 256 + abase + ty * 4 + i] = acc[i][j];
            }
        }
        __syncthreads();
        if (t < 64) {
            float M = -3.0e38f;
            #pragma unroll
            for (int i = 0; i < 16; i++) M = fmaxf(M, redM[t][i]);
            float S = 0.f;
            #pragma unroll
            for (int i = 0; i < 16; i++) S += redS[t][i] * expf(redM[t][i] - M);
            ws[OFF_PM + (size_t)(abase + t) * 80 + wt] = M;
            ws[OFF_PS + (size_t)(abase + t) * 80 + wt] = S;
        }
    } else {
        // ---- prep_g role ----
        int r = bid - 316;
        int j = t;
        bool act = j < QARG;
        float v0 = act ? rule_W[r * 2 * QARG + j] + rule_b[j] : -3.0e38f;
        float v1 = act ? rule_W[r * 2 * QARG + QARG + j] + rule_b[QARG + j] : -3.0e38f;
        float m = blockMax(fmaxf(v0, v1), scr, 4);
        float s = blockSum(act ? expf(v0 - m) + expf(v1 - m) : 0.f, scr, 4);
        float l = m + logf(s);
        if (act) {
            float av = assoc[r * QARG + j];
            ws[OFF_EGL + (size_t)j * QRES + r] = expf(v0 - l + av + larg_mask[r * QARG + j]);
            ws[OFF_EGR + (size_t)j * QRES + r] = expf(v1 - l + av + rarg_mask[r * QARG + j]);
            ((int*)ws)[OFF_LF + (size_t)j * QRES + r] = lfunc[r * QARG + j];
            ((int*)ws)[OFF_RF + (size_t)j * QRES + r] = rfunc[r * QARG + j];
        }
    }
}

// ================= MLP kernel: 2 rows/block, 4-way k-split, 1024 threads =================
__device__ __forceinline__ void mm_part(const float* __restrict__ W,
                                        const float* __restrict__ in0,
                                        const float* __restrict__ in1,
                                        int c, int q, float& o0, float& o1) {
    float a0 = 0.f, a1 = 0.f;
    int sb = q * 64;
    #pragma unroll 8
    for (int s = 0; s < 64; s += 4) {
        const float* wp = &W[(size_t)(sb + s) * STATE + c];
        float w0 = wp[0], w1 = wp[256], w2 = wp[512], w3 = wp[768];
        float4 x0 = *(const float4*)&in0[sb + s];
        float4 x1 = *(const float4*)&in1[sb + s];
        a0 += x0.x * w0 + x0.y * w1 + x0.z * w2 + x0.w * w3;
        a1 += x1.x * w0 + x1.y * w1 + x1.z * w2 + x1.w * w3;
    }
    o0 = a0; o1 = a1;
}

__global__ __launch_bounds__(1024) void mlp_kernel(
        const float* __restrict__ nt_emb,
        const float* __restrict__ sw1, const float* __restrict__ sb1,
        const float* __restrict__ r1w1, const float* __restrict__ r1b1,
        const float* __restrict__ r1w2, const float* __restrict__ r1b2,
        const float* __restrict__ r2w1, const float* __restrict__ r2b1,
        const float* __restrict__ r2w2, const float* __restrict__ r2b2,
        const float* __restrict__ sw2, const float* __restrict__ sb2,
        float* __restrict__ ws) {
    __shared__ __align__(16) float X[2][STATE], Y[2][STATE], Hr[2][STATE];
    __shared__ float P[2][4][STATE];
    __shared__ float scr[16];
    int t = threadIdx.x, c = t & 255, q = t >> 8;
    int a0 = blockIdx.x * 2;
    if (t < 512) X[t >> 8][c] = nt_emb[(a0 + (t >> 8)) * STATE + c];
    __syncthreads();
    float p0, p1, o0, o1;
    // L1: H = X@sw1 + sb1
    mm_part(sw1, X[0], X[1], c, q, p0, p1);
    P[0][q][c] = p0; P[1][q][c] = p1;
    __syncthreads();
    o0 = P[0][0][c] + P[0][1][c] + P[0][2][c] + P[0][3][c] + sb1[c];
    o1 = P[1][0][c] + P[1][1][c] + P[1][2][c] + P[1][3][c] + sb1[c];
    __syncthreads();
    if (q == 0) { Hr[0][c] = o0; Hr[1][c] = o1; }
    __syncthreads();
    // L2: t1 = relu(H@r1w1 + b)
    mm_part(r1w1, Hr[0], Hr[1], c, q, p0, p1);
    P[0][q][c] = p0; P[1][q][c] = p1;
    __syncthreads();
    o0 = P[0][0][c] + P[0][1][c] + P[0][2][c] + P[0][3][c] + r1b1[c];
    o1 = P[1][0][c] + P[1][1][c] + P[1][2][c] + P[1][3][c] + r1b1[c];
    __syncthreads();
    if (q == 0) { Y[0][c] = fmaxf(o0, 0.f); Y[1][c] = fmaxf(o1, 0.f); }
    __syncthreads();
    // L3: H += relu(t1@r1w2 + b)
    mm_part(r1w2, Y[0], Y[1], c, q, p0, p1);
    P[0][q][c] = p0; P[1][q][c] = p1;
    __syncthreads();
    o0 = P[0][0][c] + P[0][1][c] + P[0][2][c] + P[0][3][c] + r1b2[c];
    o1 = P[1][0][c] + P[1][1][c] + P[1][2][c] + P[1][3][c] + r1b2[c];
    __syncthreads();
    if (q == 0) { Hr[0][c] += fmaxf(o0, 0.f); Hr[1][c] += fmaxf(o1, 0.f); }
    __syncthreads();
    // L4: t2 = relu(H@r2w1 + b)
    mm_part(r2w1, Hr[0], Hr[1], c, q, p0, p1);
    P[0][q][c] = p0; P[1][q][c] = p1;
    __syncthreads();
    o0 = P[0][0][c] + P[0][1][c] + P[0][2][c] + P[0][3][c] + r2b1[c];
    o1 = P[1][0][c] + P[1][1][c] + P[1][2][c] + P[1][3][c] + r2b1[c];
    __syncthreads();
    if (q == 0) { Y[0][c] = fmaxf(o0, 0.f); Y[1][c] = fmaxf(o1, 0.f); }
    __syncthreads();
    // L5: h = H + relu(t2@r2w2 + b)
    mm_part(r2w2, Y[0], Y[1], c, q, p0, p1);
    P[0][q][c] = p0; P[1][q][c] = p1;
    __syncthreads();
    o0 = P[0][0][c] + P[0][1][c] + P[0][2][c] + P[0][3][c] + r2b2[c];
    o1 = P[1][0][c] + P[1][1][c] + P[1][2][c] + P[1][3][c] + r2b2[c];
    __syncthreads();
    float h0 = Hr[0][c] + fmaxf(o0, 0.f);
    float h1 = Hr[1][c] + fmaxf(o1, 0.f);
    float w20 = sw2[c * 2 + 0], w21 = sw2[c * 2 + 1];
    float u00 = blockSum((q == 0) ? h0 * w20 : 0.f, scr, 16) + sb2[0];
    float u01 = blockSum((q == 0) ? h0 * w21 : 0.f, scr, 16) + sb2[1];
    float u10 = blockSum((q == 0) ? h1 * w20 : 0.f, scr, 16) + sb2[0];
    float u11 = blockSum((q == 0) ? h1 * w21 : 0.f, scr, 16) + sb2[1];
    if (t == 0) {
        float mm = fmaxf(u00, u01);
        float l = mm + logf(expf(u00 - mm) + expf(u01 - mm));
        ws[OFF_S0 + a0] = u00 - l;
        ws[OFF_S1 + a0] = u01 - l;
    } else if (t == 1) {
        float mm = fmaxf(u10, u11);
        float l = mm + logf(expf(u10 - mm) + expf(u11 - mm));
        ws[OFF_S0 + a0 + 1] = u10 - l;
        ws[OFF_S1 + a0 + 1] = u11 - l;
    }
}

// ================= cooperative kernel: chart0 + all 15 levels + root =================
__global__ __launch_bounds__(512) void coop_kernel(
        float* __restrict__ ws, const int* __restrict__ argpc,
        const int* __restrict__ res2all,
        const float* __restrict__ root_w, const float* __restrict__ root_b,
        float* __restrict__ out) {
    cg::grid_group grid = cg::this_grid();
    __shared__ __align__(16) float eAf[15 * 256];
    __shared__ __align__(16) float eBb[15 * 32];
    __shared__ __align__(16) float Wt[32 * 256];
    __shared__ float smA[15], smB[15];
    __shared__ float Sred[512];
    __shared__ float outrow[256];
    __shared__ float scrm[8];
    __shared__ float lseS[256], s1S[256];
    __shared__ int flag;
    int t = threadIdx.x;

    // zero ACC + CNT
    for (size_t i = (size_t)blockIdx.x * 512 + t; i < ACC_SZ + 960; i += (size_t)GRID_COOP * 512)
        ((int*)ws)[OFF_ACC + i] = 0;

    // chart0: blocks 0..63, two (b,tp) items per block
    if (blockIdx.x < 64) {
        if (t < 256) {
            int a = t;
            const float* pm = &ws[OFF_PM + (size_t)a * 80];
            const float* ps = &ws[OFF_PS + (size_t)a * 80];
            float M = -3.0e38f;
            for (int w = 0; w < 76; w += 4) {
                float4 v = *(const float4*)&pm[w];
                M = fmaxf(M, fmaxf(fmaxf(v.x, v.y), fmaxf(v.z, v.w)));
            }
            M = fmaxf(M, fmaxf(pm[76], fmaxf(pm[77], pm[78])));
            float S = 0.f;
            for (int w = 0; w < 76; w += 4) {
                float4 v = *(const float4*)&pm[w];
                float4 u = *(const float4*)&ps[w];
                S += u.x * expf(v.x - M) + u.y * expf(v.y - M) +
                     u.z * expf(v.z - M) + u.w * expf(v.w - M);
            }
            S += ps[76] * expf(pm[76] - M) + ps[77] * expf(pm[77] - M) + ps[78] * expf(pm[78] - M);
            lseS[a] = M + logf(S);
            s1S[a] = ws[OFF_S1 + a];
        }
        __syncthreads();
        int half = t >> 8, tt = t & 255;
        int item = blockIdx.x * 2 + half;
        int b = item >> 4, tp = item & 15;
        float val = ws[OFF_TERM + (size_t)item * 256 + tt] - lseS[tt] + s1S[tt];
        ws[chIdx(0, tp, b) + tt] = val;
        float wv = waveMax(val);
        if ((t & 63) == 0) scrm[t >> 6] = wv;
        __syncthreads();
        if (t == 0)
            ws[OFF_RMAX + (size_t)(0 * 16 + tp) * 8 + b] =
                fmaxf(fmaxf(scrm[0], scrm[1]), fmaxf(scrm[2], scrm[3]));
        if (t == 256)
            ws[OFF_RMAX + (size_t)(0 * 16 + tp) * 8 + b] =
                fmaxf(fmaxf(scrm[4], scrm[5]), fmaxf(scrm[6], scrm[7]));
    }
    __threadfence();
    grid.sync();

    int lvbase = 0;
    for (int ell = 2; ell <= T_; ell++) {
        __threadfence();
        int n = T_ - ell + 1, K = ell - 1;
        int items = n * 8 * 12;
        for (int item = blockIdx.x; item < items; item += GRID_COOP) {
            __syncthreads();
            int sb = item / 12, wj = item % 12;
            int s = sb >> 3, b = sb & 7;
            int which = wj / 6, jt = wj % 6, jbase = jt * 32;
            int slot = (lvbase + s) * 8 + b;

            if (t < K) {
                float mL = ws[OFF_RMAX + (size_t)(t * 16 + s) * 8 + b];
                float mR = ws[OFF_RMAX + (size_t)((ell - t - 2) * 16 + (s + t + 1)) * 8 + b];
                smA[t] = which ? mR : mL;
                smB[t] = which ? mL : mR;
            }
            __syncthreads();
            float m = -3.0e38f;
            for (int kp = 0; kp < K; kp++) m = fmaxf(m, smA[kp] + smB[kp]);

            for (int i = t; i < K * 256; i += 512) {
                int kp = i >> 8, a = i & 255;
                size_t rowA = which ? chIdx(ell - kp - 2, s + kp + 1, b) : chIdx(kp, s, b);
                eAf[i] = expf(ws[rowA + a] - smA[kp]);
            }
            if (t < K * 32) {
                int kp = t >> 5, jj = t & 31;
                int ap = argpc[jbase + jj];
                size_t rowB = which ? chIdx(kp, s, b) : chIdx(ell - kp - 2, s + kp + 1, b);
                eBb[t] = expf(ws[rowB + ap] - (m - smA[kp]));
            }
            __syncthreads();

            // GEMM: Wt[jj][a] = sum_k eAf[k][a] * eBb[k][jj]
            {
                int ag = t & 63, jg = t >> 6;
                int a0 = ag * 4, j0 = jg * 4;
                float acc[4][4];
                #pragma unroll
                for (int x = 0; x < 4; x++)
                    #pragma unroll
                    for (int y = 0; y < 4; y++) acc[x][y] = 0.f;
                for (int kp = 0; kp < K; kp++) {
                    float4 av = *(const float4*)&eAf[kp * 256 + a0];
                    float4 bv = *(const float4*)&eBb[kp * 32 + j0];
                    acc[0][0] += bv.x * av.x; acc[0][1] += bv.x * av.y; acc[0][2] += bv.x * av.z; acc[0][3] += bv.x * av.w;
                    acc[1][0] += bv.y * av.x; acc[1][1] += bv.y * av.y; acc[1][2] += bv.y * av.z; acc[1][3] += bv.y * av.w;
                    acc[2][0] += bv.z * av.x; acc[2][1] += bv.z * av.y; acc[2][2] += bv.z * av.z; acc[2][3] += bv.z * av.w;
                    acc[3][0] += bv.w * av.x; acc[3][1] += bv.w * av.y; acc[3][2] += bv.w * av.z; acc[3][3] += bv.w * av.w;
                }
                #pragma unroll
                for (int x = 0; x < 4; x++)
                    *(float4*)&Wt[(size_t)(j0 + x) * 256 + a0] =
                        make_float4(acc[x][0], acc[x][1], acc[x][2], acc[x][3]);
            }
            __syncthreads();

            // gather: sum_j eG[j][r] * Wt[jj][idx[j][r]]
            {
                int r = t & 127, jq = t >> 7;
                const float* eG  = ws + (which ? OFF_EGL : OFF_EGR);
                const int* idxT = ((const int*)ws) + (which ? OFF_RF : OFF_LF);
                float sum = 0.f;
                #pragma unroll
                for (int i = 0; i < 8; i++) {
                    int jj = jq * 8 + i;
                    int j = jbase + jj;
                    float gv = eG[(size_t)j * QRES + r];
                    int idx = idxT[(size_t)j * QRES + r];
                    sum += gv * Wt[(size_t)jj * 256 + idx];
                }
                Sred[t] = sum;
            }
            __syncthreads();
            if (t < 128)
                atomicAdd(&ws[OFF_ACC + (size_t)slot * 128 + t],
                          Sred[t] + Sred[t + 128] + Sred[t + 256] + Sred[t + 384]);
            __syncthreads();
            if (t == 0) {
                __threadfence();
                int old = atomicAdd(&((int*)ws)[OFF_CNT + slot], 1);
                flag = (old == 11);
            }
            __syncthreads();
            if (!flag) continue;
            __threadfence();

            // last-arrival finalize
            if (t < 256) outrow[t] = NEGV;
            __syncthreads();
            float pm = -3.0e38f;
            if (t < 128) {
                float S = __hip_atomic_load(&ws[OFF_ACC + (size_t)slot * 128 + t],
                                            __ATOMIC_RELAXED, __HIP_MEMORY_SCOPE_AGENT);
                float parent = logf(S) + m + ws[OFF_S0 + res2all[t]];
                outrow[res2all[t]] = parent;
                pm = parent;
            }
            float wm = waveMax(pm);
            if ((t & 63) == 0) scrm[t >> 6] = wm;
            __syncthreads();
            if (t < 256) ws[chIdx(ell - 1, s, b) + t] = outrow[t];
            if (t == 0) {
                float M = scrm[0];
                #pragma unroll
                for (int i = 1; i < 8; i++) M = fmaxf(M, scrm[i]);
                ws[OFF_RMAX + (size_t)((ell - 1) * 16 + s) * 8 + b] = M;
            }
            __threadfence();
        }
        grid.sync();
        lvbase += n;
    }

    // root
    __threadfence();
    if (blockIdx.x == 0) {
        float rv = (t < 256) ? root_w[t] + root_b[t] : -3.0e38f;
        float M = blockMax(rv, scrm, 8);
        float S = blockSum((t < 256) ? expf(rv - M) : 0.f, scrm, 8);
        float lroot = M + logf(S);
        for (int b = 0; b < 8; b++) {
            float v = (t < 256) ? ws[chIdx(T_ - 1, 0, b) + t] + rv - lroot : -3.0e38f;
            float m2 = blockMax(v, scrm, 8);
            float s2 = blockSum((t < 256) ? expf(v - m2) : 0.f, scrm, 8);
            if (t == 0) out[b] = m2 + logf(s2);
        }
    }
}

extern "C" void kernel_launch(void* const* d_in, const int* in_sizes, int n_in,
                              void* d_out, int out_size, void* d_ws, size_t ws_size,
                              hipStream_t stream) {
    const int*   words   = (const int*)  d_in[0];
    const float* nt_emb  = (const float*)d_in[1];
    const float* W_emit  = (const float*)d_in[2];
    const float* b_emit  = (const float*)d_in[3];
    const float* rule_W  = (const float*)d_in[4];
    const float* rule_b  = (const float*)d_in[5];
    const float* assoc   = (const float*)d_in[6];
    const float* root_w  = (const float*)d_in[7];
    const float* root_b  = (const float*)d_in[8];
    const float* sw1     = (const float*)d_in[9];
    const float* sb1     = (const float*)d_in[10];
    const float* r1w1    = (const float*)d_in[11];
    const float* r1b1    = (const float*)d_in[12];
    const float* r1w2    = (const float*)d_in[13];
    const float* r1b2    = (const float*)d_in[14];
    const float* r2w1    = (const float*)d_in[15];
    const float* r2b1    = (const float*)d_in[16];
    const float* r2w2    = (const float*)d_in[17];
    const float* r2b2    = (const float*)d_in[18];
    const float* sw2     = (const float*)d_in[19];
    const float* sb2     = (const float*)d_in[20];
    const int*   lfunc   = (const int*)  d_in[21];
    const int*   rfunc   = (const int*)  d_in[22];
    const int*   argpc   = (const int*)  d_in[23];
    const int*   res2all = (const int*)  d_in[24];
    const float* larg_m  = (const float*)d_in[25];
    const float* rarg_m  = (const float*)d_in[26];
    float* ws  = (float*)d_ws;
    float* out = (float*)d_out;

    front_kernel<<<dim3(316 + 128), dim3(256), 0, stream>>>(
        words, nt_emb, W_emit, b_emit, rule_W, rule_b, assoc, larg_m, rarg_m,
        lfunc, rfunc, ws);
    mlp_kernel<<<dim3(QALL / 2), dim3(1024), 0, stream>>>(
        nt_emb, sw1, sb1, r1w1, r1b1, r1w2, r1b2,
        r2w1, r2b1, r2w2, r2b2, sw2, sb2, ws);
    void* cargs[] = { (void*)&ws, (void*)&argpc, (void*)&res2all,
                      (void*)&root_w, (void*)&root_b, (void*)&out };
    hipLaunchCooperativeKernel(reinterpret_cast<void*>(coop_kernel),
                               dim3(GRID_COOP), dim3(512), cargs, 0, stream);
}

// Round 5
// 1076.547 us; speedup vs baseline: 1.9498x; 1.9498x over previous
//
#include <hip/hip_runtime.h>
#include <hip/hip_cooperative_groups.h>
#include <math.h>

#define NEGV -10000000.0f

constexpr int B_ = 8, T_ = 16;
constexpr int QALL = 256, QRES = 128, QARG = 192;
constexpr int STATE = 256, VOCAB = 10000;
constexpr int WT = 128;
constexpr int NWT = (VOCAB + WT - 1) / WT;   // 79
constexpr int NTERM = B_ * T_;               // 128
constexpr int GRID_COOP = 240;
constexpr int NITEMS = 128 + 960 + 1;        // chart0 + spans + root = 1089

// ---- workspace layout (units of 4 bytes) ----
constexpr size_t OFF_CHART = 0;                                    // chart[lev][s][b][a]
constexpr size_t CHART_SZ  = (size_t)T_ * T_ * B_ * QALL;
constexpr size_t OFF_EGR   = OFF_CHART + CHART_SZ;                 // exp(G_rarg) [j][r]
constexpr size_t OFF_EGL   = OFF_EGR + (size_t)QARG * QRES;
constexpr size_t OFF_LF    = OFF_EGL + (size_t)QARG * QRES;        // lfunc T [j][r] (int)
constexpr size_t OFF_RF    = OFF_LF + (size_t)QARG * QRES;
constexpr size_t OFF_S0    = OFF_RF + (size_t)QARG * QRES;         // split0 (256)
constexpr size_t OFF_S1    = OFF_S0 + QALL;                        // split1 (256)
constexpr size_t OFF_PM    = OFF_S1 + QALL;                        // emit partial max [a][80]
constexpr size_t OFF_PS    = OFF_PM + (size_t)QALL * 80;
constexpr size_t OFF_TERM  = OFF_PS + (size_t)QALL * 80;           // raw term logits [item][a]
constexpr size_t OFF_RMAX  = OFF_TERM + (size_t)NTERM * QALL;      // rowmax[lev][s][b]
constexpr size_t OFF_FLAG  = OFF_RMAX + (size_t)T_ * T_ * B_;      // ready flags [lev][s][b] (2048 ints)

__device__ __forceinline__ size_t chIdx(int lev, int s, int b) {
    return OFF_CHART + ((size_t)((lev * 16 + s) * 8 + b)) * 256;
}

__device__ __forceinline__ float waveMax(float v) {
    #pragma unroll
    for (int m = 32; m >= 1; m >>= 1) v = fmaxf(v, __shfl_xor(v, m, 64));
    return v;
}
__device__ __forceinline__ float waveSum(float v) {
    #pragma unroll
    for (int m = 32; m >= 1; m >>= 1) v += __shfl_xor(v, m, 64);
    return v;
}
__device__ __forceinline__ float blockMax(float v, float* scr, int nw) {
    int lane = threadIdx.x & 63, w = threadIdx.x >> 6;
    v = waveMax(v);
    if (lane == 0) scr[w] = v;
    __syncthreads();
    float r = scr[0];
    for (int i = 1; i < nw; i++) r = fmaxf(r, scr[i]);
    __syncthreads();
    return r;
}
__device__ __forceinline__ float blockSum(float v, float* scr, int nw) {
    int lane = threadIdx.x & 63, w = threadIdx.x >> 6;
    v = waveSum(v);
    if (lane == 0) scr[w] = v;
    __syncthreads();
    float r = 0.f;
    for (int i = 0; i < nw; i++) r += scr[i];
    __syncthreads();
    return r;
}

__device__ __forceinline__ void spinFlag(int* f) {
    while (__hip_atomic_load(f, __ATOMIC_ACQUIRE, __HIP_MEMORY_SCOPE_AGENT) == 0)
        __builtin_amdgcn_s_sleep(2);
}

// ================= front kernel: mlp (256) + emit (316) + prep_g/flag-zero (128) =================
__device__ __forceinline__ float mv256(const float* __restrict__ X,
                                       const float* __restrict__ W, int t) {
    float a0 = 0.f, a1 = 0.f, a2 = 0.f, a3 = 0.f;
    #pragma unroll 16
    for (int s = 0; s < STATE; s += 4) {
        float4 x = *(const float4*)&X[s];
        a0 += x.x * W[(size_t)(s + 0) * STATE + t];
        a1 += x.y * W[(size_t)(s + 1) * STATE + t];
        a2 += x.z * W[(size_t)(s + 2) * STATE + t];
        a3 += x.w * W[(size_t)(s + 3) * STATE + t];
    }
    return (a0 + a1) + (a2 + a3);
}

__global__ __launch_bounds__(256) void front_kernel(
        const int* __restrict__ words, const float* __restrict__ nt_emb,
        const float* __restrict__ W_emit, const float* __restrict__ b_emit,
        const float* __restrict__ rule_W, const float* __restrict__ rule_b,
        const float* __restrict__ assoc,
        const float* __restrict__ larg_mask, const float* __restrict__ rarg_mask,
        const int* __restrict__ lfunc, const int* __restrict__ rfunc,
        const float* __restrict__ sw1, const float* __restrict__ sb1,
        const float* __restrict__ r1w1, const float* __restrict__ r1b1,
        const float* __restrict__ r1w2, const float* __restrict__ r1b2,
        const float* __restrict__ r2w1, const float* __restrict__ r2b1,
        const float* __restrict__ r2w2, const float* __restrict__ r2b2,
        const float* __restrict__ sw2, const float* __restrict__ sb2,
        float* __restrict__ ws) {
    __shared__ float As[16][64];
    __shared__ float Bs[16][128];
    __shared__ float redM[64][16], redS[64][16];
    __shared__ int wordsS[128];
    __shared__ __align__(16) float Xs[256], Hs[256], Ys[256];
    __shared__ float scr[4];
    int bid = blockIdx.x, t = threadIdx.x;

    if (bid < 256) {
        // ---- MLP role: one nt_emb row per block ----
        int a = bid;
        Xs[t] = nt_emb[(size_t)a * STATE + t];
        __syncthreads();
        float h = mv256(Xs, sw1, t) + sb1[t];
        Hs[t] = h;
        __syncthreads();
        float u = fmaxf(mv256(Hs, r1w1, t) + r1b1[t], 0.f);
        Ys[t] = u;
        __syncthreads();
        h = h + fmaxf(mv256(Ys, r1w2, t) + r1b2[t], 0.f);
        Hs[t] = h;
        __syncthreads();
        u = fmaxf(mv256(Hs, r2w1, t) + r2b1[t], 0.f);
        Ys[t] = u;
        __syncthreads();
        h = h + fmaxf(mv256(Ys, r2w2, t) + r2b2[t], 0.f);
        float u0 = blockSum(h * sw2[t * 2 + 0], scr, 4) + sb2[0];
        float u1 = blockSum(h * sw2[t * 2 + 1], scr, 4) + sb2[1];
        if (t == 0) {
            float mm = fmaxf(u0, u1);
            float l = mm + logf(expf(u0 - mm) + expf(u1 - mm));
            ws[OFF_S0 + a] = u0 - l;
            ws[OFF_S1 + a] = u1 - l;
        }
    } else if (bid < 256 + 316) {
        // ---- emit role ----
        int eb = bid - 256;
        int wt = eb % 79, at = eb / 79;
        int tx = t & 15, ty = t >> 4;
        if (t < 128) wordsS[t] = words[t];
        float acc[4][8];
        #pragma unroll
        for (int i = 0; i < 4; i++)
            #pragma unroll
            for (int j = 0; j < 8; j++) acc[i][j] = 0.f;
        int wbase = wt * WT, abase = at * 64;
        for (int k0 = 0; k0 < STATE; k0 += 16) {
            {
                int idx = t * 4;
                int kk = idx & 15, aa = idx >> 4;
                float4 v = *(const float4*)&nt_emb[(size_t)(abase + aa) * STATE + k0 + kk];
                As[kk + 0][aa] = v.x; As[kk + 1][aa] = v.y; As[kk + 2][aa] = v.z; As[kk + 3][aa] = v.w;
            }
            {
                int idx = t * 8;
                int kk = idx >> 7, ww = idx & 127;
                int w = wbase + ww;
                const float* src = &W_emit[(size_t)(k0 + kk) * VOCAB + w];
                float4 v0, v1;
                if (w + 7 < VOCAB) {
                    v0 = *(const float4*)src;
                    v1 = *(const float4*)(src + 4);
                } else {
                    float tv[8];
                    #pragma unroll
                    for (int q = 0; q < 8; q++) tv[q] = (w + q < VOCAB) ? src[q] : 0.f;
                    v0 = make_float4(tv[0], tv[1], tv[2], tv[3]);
                    v1 = make_float4(tv[4], tv[5], tv[6], tv[7]);
                }
                float* dst = &Bs[kk][ww];
                ((float4*)dst)[0] = v0;
                ((float4*)dst)[1] = v1;
            }
            __syncthreads();
            #pragma unroll
            for (int kk = 0; kk < 16; kk++) {
                float a4[4], b8[8];
                #pragma unroll
                for (int i = 0; i < 4; i++) a4[i] = As[kk][ty * 4 + i];
                #pragma unroll
                for (int j = 0; j < 8; j++) b8[j] = Bs[kk][tx * 8 + j];
                #pragma unroll
                for (int i = 0; i < 4; i++)
                    #pragma unroll
                    for (int j = 0; j < 8; j++) acc[i][j] += a4[i] * b8[j];
            }
            __syncthreads();
        }
        float be[8];
        #pragma unroll
        for (int j = 0; j < 8; j++) {
            int w = wbase + tx * 8 + j;
            be[j] = (w < VOCAB) ? b_emit[w] : 0.f;
        }
        #pragma unroll
        for (int i = 0; i < 4; i++) {
            float mloc = -3.0e38f;
            #pragma unroll
            for (int j = 0; j < 8; j++) {
                int w = wbase + tx * 8 + j;
                if (w < VOCAB) {
                    float v = acc[i][j] + be[j];
                    acc[i][j] = v;
                    mloc = fmaxf(mloc, v);
                }
            }
            float sloc = 0.f;
            #pragma unroll
            for (int j = 0; j < 8; j++) {
                int w = wbase + tx * 8 + j;
                if (w < VOCAB) sloc += expf(acc[i][j] - mloc);
            }
            redM[ty * 4 + i][tx] = mloc;
            redS[ty * 4 + i][tx] = sloc;
        }
        // raw term logits for word positions in this w-tile
        for (int it = 0; it < 128; it++) {
            int w = wordsS[it];
            int d = w - wbase;
            if (d >= 0 && d < 128 && (d >> 3) == tx) {
                int j = d & 7;
                #pragma unroll
                for (int i = 0; i < 4; i++)
                    ws[OFF_TERM + (size_t)it * 256 + abase + ty * 4 + i] = acc[i][j];
            }
        }
        __syncthreads();
        if (t < 64) {
            float M = -3.0e38f;
            #pragma unroll
            for (int i = 0; i < 16; i++) M = fmaxf(M, redM[t][i]);
            float S = 0.f;
            #pragma unroll
            for (int i = 0; i < 16; i++) S += redS[t][i] * expf(redM[t][i] - M);
            ws[OFF_PM + (size_t)(abase + t) * 80 + wt] = M;
            ws[OFF_PS + (size_t)(abase + t) * 80 + wt] = S;
        }
    } else {
        // ---- prep_g role + flag zeroing ----
        int r = bid - 572;
        int zi = r * 256 + t;
        if (zi < 2048) ((int*)ws)[OFF_FLAG + zi] = 0;
        int j = t;
        bool act = j < QARG;
        float v0 = act ? rule_W[r * 2 * QARG + j] + rule_b[j] : -3.0e38f;
        float v1 = act ? rule_W[r * 2 * QARG + QARG + j] + rule_b[QARG + j] : -3.0e38f;
        float m = blockMax(fmaxf(v0, v1), scr, 4);
        float s = blockSum(act ? expf(v0 - m) + expf(v1 - m) : 0.f, scr, 4);
        float l = m + logf(s);
        if (act) {
            float av = assoc[r * QARG + j];
            ws[OFF_EGL + (size_t)j * QRES + r] = expf(v0 - l + av + larg_mask[r * QARG + j]);
            ws[OFF_EGR + (size_t)j * QRES + r] = expf(v1 - l + av + rarg_mask[r * QARG + j]);
            ((int*)ws)[OFF_LF + (size_t)j * QRES + r] = lfunc[r * QARG + j];
            ((int*)ws)[OFF_RF + (size_t)j * QRES + r] = rfunc[r * QARG + j];
        }
    }
}

// ================= cooperative kernel: flag-driven chart build =================
__global__ __launch_bounds__(1024, 4) void coop_kernel(
        float* __restrict__ ws, const int* __restrict__ argpc,
        const int* __restrict__ res2all,
        const float* __restrict__ root_w, const float* __restrict__ root_b,
        float* __restrict__ out) {
    __shared__ __align__(16) float eLf[15 * 256];
    __shared__ __align__(16) float eRf[15 * 256];
    __shared__ __align__(16) float Wt[16 * 256];
    __shared__ float Bt[2][15 * 16];
    __shared__ float Sred[1024];
    __shared__ float outrow[256];
    __shared__ float smL[15], smR[15], scS[15];
    __shared__ float scrm[16];
    int t = threadIdx.x;
    int* flags = (int*)ws + OFF_FLAG;

    for (int item = blockIdx.x; item < NITEMS; item += GRID_COOP) {
        if (item < 128) {
            // ---------- chart0 item: (b, tp) ----------
            int b = item >> 4, tp = item & 15;
            float val = -3.0e38f;
            if (t < 256) {
                const float* pm = &ws[OFF_PM + (size_t)t * 80];
                const float* ps = &ws[OFF_PS + (size_t)t * 80];
                float M = -3.0e38f;
                for (int w = 0; w < 76; w += 4) {
                    float4 v = *(const float4*)&pm[w];
                    M = fmaxf(M, fmaxf(fmaxf(v.x, v.y), fmaxf(v.z, v.w)));
                }
                M = fmaxf(M, fmaxf(pm[76], fmaxf(pm[77], pm[78])));
                float S = 0.f;
                for (int w = 0; w < 76; w += 4) {
                    float4 v = *(const float4*)&pm[w];
                    float4 u = *(const float4*)&ps[w];
                    S += u.x * expf(v.x - M) + u.y * expf(v.y - M) +
                         u.z * expf(v.z - M) + u.w * expf(v.w - M);
                }
                S += ps[76] * expf(pm[76] - M) + ps[77] * expf(pm[77] - M) +
                     ps[78] * expf(pm[78] - M);
                float lse = M + logf(S);
                val = ws[OFF_TERM + (size_t)item * 256 + t] - lse + ws[OFF_S1 + t];
                ws[chIdx(0, tp, b) + t] = val;
            }
            float wv = waveMax(val);
            if ((t & 63) == 0) scrm[t >> 6] = wv;
            __syncthreads();
            if (t == 0)
                ws[OFF_RMAX + (size_t)(0 * 16 + tp) * 8 + b] =
                    fmaxf(fmaxf(scrm[0], scrm[1]), fmaxf(scrm[2], scrm[3]));
            __syncthreads();
            if (t == 0)
                __hip_atomic_store(&flags[0 * 128 + tp * 8 + b], 1,
                                   __ATOMIC_RELEASE, __HIP_MEMORY_SCOPE_AGENT);
        } else if (item == NITEMS - 1) {
            // ---------- root item ----------
            if (t < 8) spinFlag(&flags[15 * 128 + 0 * 8 + t]);
            __syncthreads();
            float rv = (t < 256) ? root_w[t] + root_b[t] : -3.0e38f;
            float M = blockMax(rv, scrm, 16);
            float S = blockSum((t < 256) ? expf(rv - M) : 0.f, scrm, 16);
            float lroot = M + logf(S);
            for (int b = 0; b < 8; b++) {
                float v = (t < 256) ? ws[chIdx(15, 0, b) + t] + rv - lroot : -3.0e38f;
                float m2 = blockMax(v, scrm, 16);
                float s2 = blockSum((t < 256) ? expf(v - m2) : 0.f, scrm, 16);
                if (t == 0) out[b] = m2 + logf(s2);
            }
        } else {
            // ---------- span item ----------
            int e = 2, base = 128;
            while (item >= base + (17 - e) * 8) { base += (17 - e) * 8; e++; }
            int ell = e;
            int idx = item - base;
            int s = idx >> 3, b = idx & 7;
            int K = ell - 1;

            // wait for the 2K producer rows
            if (t < K) {
                spinFlag(&flags[t * 128 + s * 8 + b]);
            } else if (t >= 128 && t < 128 + K) {
                int kp = t - 128;
                spinFlag(&flags[(ell - kp - 2) * 128 + (s + kp + 1) * 8 + b]);
            }
            __syncthreads();

            // row maxes + global scale
            if (t < K) smL[t] = ws[OFF_RMAX + (size_t)(t * 16 + s) * 8 + b];
            else if (t >= 128 && t < 128 + K) {
                int kp = t - 128;
                smR[kp] = ws[OFF_RMAX + (size_t)((ell - kp - 2) * 16 + (s + kp + 1)) * 8 + b];
            }
            __syncthreads();
            float m = -3.0e38f;
            for (int kp = 0; kp < K; kp++) m = fmaxf(m, smL[kp] + smR[kp]);
            if (t < K) scS[t] = expf(smL[t] + smR[t] - m);

            // stage exp'd rows
            for (int i = t; i < K * 256; i += 1024) {
                int kp = i >> 8, a = i & 255;
                eLf[i] = expf(ws[chIdx(kp, s, b) + a] - smL[kp]);
                eRf[i] = expf(ws[chIdx(ell - kp - 2, s + kp + 1, b) + a] - smR[kp]);
            }
            __syncthreads();   // rows + scS ready

            // pipelined tiles: 2 which × 12 j-tiles of 16
            auto stageBt = [&](int i) {
                int wh = i / 12, jbase = (i % 12) * 16;
                const float* src = wh ? eLf : eRf;   // broadcast side
                for (int x = t; x < K * 16; x += 1024) {
                    int kp = x >> 4, jj = x & 15;
                    int ap = argpc[jbase + jj];
                    Bt[i & 1][x] = src[kp * 256 + ap] * scS[kp];
                }
            };
            stageBt(0);
            __syncthreads();
            float accg = 0.f;
            int r = t & 127, jq = t >> 7;
            int a0 = (t & 63) * 4, jg = t >> 6;   // jg in 0..15
            for (int i = 0; i < 24; i++) {
                int wh = i / 12, jbase = (i % 12) * 16;
                const float* Af = wh ? eRf : eLf;
                float ac0 = 0.f, ac1 = 0.f, ac2 = 0.f, ac3 = 0.f;
                for (int kp = 0; kp < K; kp++) {
                    float bv = Bt[i & 1][kp * 16 + jg];
                    float4 av = *(const float4*)&Af[kp * 256 + a0];
                    ac0 += bv * av.x; ac1 += bv * av.y; ac2 += bv * av.z; ac3 += bv * av.w;
                }
                __syncthreads();   // prev gather done reading Wt
                *(float4*)&Wt[(size_t)jg * 256 + a0] = make_float4(ac0, ac1, ac2, ac3);
                if (i + 1 < 24) stageBt(i + 1);
                __syncthreads();   // Wt + Bt(i+1) ready
                const float* eG  = ws + (wh ? OFF_EGL : OFF_EGR);
                const int* idxT = (const int*)ws + (wh ? OFF_RF : OFF_LF);
                #pragma unroll
                for (int q = 0; q < 2; q++) {
                    int jj = jq * 2 + q;
                    int j = jbase + jj;
                    float gv = eG[(size_t)j * QRES + r];
                    int ix = idxT[(size_t)j * QRES + r];
                    accg += gv * Wt[(size_t)jj * 256 + ix];
                }
            }
            Sred[t] = accg;
            if (t < 256) outrow[t] = NEGV;
            __syncthreads();
            float pm = -3.0e38f;
            if (t < 128) {
                float S = 0.f;
                #pragma unroll
                for (int g = 0; g < 8; g++) S += Sred[t + 128 * g];
                float parent = logf(S) + m + ws[OFF_S0 + res2all[t]];
                outrow[res2all[t]] = parent;
                pm = parent;
            }
            float wv = waveMax(pm);
            if ((t & 63) == 0) scrm[t >> 6] = wv;
            __syncthreads();
            if (t < 256) ws[chIdx(ell - 1, s, b) + t] = outrow[t];
            if (t == 0)
                ws[OFF_RMAX + (size_t)((ell - 1) * 16 + s) * 8 + b] = fmaxf(scrm[0], scrm[1]);
            __syncthreads();   // drain row/rmax stores (vmcnt(0) before barrier)
            if (t == 0)
                __hip_atomic_store(&flags[(ell - 1) * 128 + s * 8 + b], 1,
                                   __ATOMIC_RELEASE, __HIP_MEMORY_SCOPE_AGENT);
        }
        __syncthreads();
    }
}

extern "C" void kernel_launch(void* const* d_in, const int* in_sizes, int n_in,
                              void* d_out, int out_size, void* d_ws, size_t ws_size,
                              hipStream_t stream) {
    const int*   words   = (const int*)  d_in[0];
    const float* nt_emb  = (const float*)d_in[1];
    const float* W_emit  = (const float*)d_in[2];
    const float* b_emit  = (const float*)d_in[3];
    const float* rule_W  = (const float*)d_in[4];
    const float* rule_b  = (const float*)d_in[5];
    const float* assoc   = (const float*)d_in[6];
    const float* root_w  = (const float*)d_in[7];
    const float* root_b  = (const float*)d_in[8];
    const float* sw1     = (const float*)d_in[9];
    const float* sb1     = (const float*)d_in[10];
    const float* r1w1    = (const float*)d_in[11];
    const float* r1b1    = (const float*)d_in[12];
    const float* r1w2    = (const float*)d_in[13];
    const float* r1b2    = (const float*)d_in[14];
    const float* r2w1    = (const float*)d_in[15];
    const float* r2b1    = (const float*)d_in[16];
    const float* r2w2    = (const float*)d_in[17];
    const float* r2b2    = (const float*)d_in[18];
    const float* sw2     = (const float*)d_in[19];
    const float* sb2     = (const float*)d_in[20];
    const int*   lfunc   = (const int*)  d_in[21];
    const int*   rfunc   = (const int*)  d_in[22];
    const int*   argpc   = (const int*)  d_in[23];
    const int*   res2all = (const int*)  d_in[24];
    const float* larg_m  = (const float*)d_in[25];
    const float* rarg_m  = (const float*)d_in[26];
    float* ws  = (float*)d_ws;
    float* out = (float*)d_out;

    front_kernel<<<dim3(256 + 316 + 128), dim3(256), 0, stream>>>(
        words, nt_emb, W_emit, b_emit, rule_W, rule_b, assoc, larg_m, rarg_m,
        lfunc, rfunc, sw1, sb1, r1w1, r1b1, r1w2, r1b2,
        r2w1, r2b1, r2w2, r2b2, sw2, sb2, ws);

    void* cargs[] = { (void*)&ws, (void*)&argpc, (void*)&res2all,
                      (void*)&root_w, (void*)&root_b, (void*)&out };
    hipLaunchCooperativeKernel(reinterpret_cast<void*>(coop_kernel),
                               dim3(GRID_COOP), dim3(1024), cargs, 0, stream);
}